// Round 3
// baseline (3613.980 us; speedup 1.0000x reference)
//
#include <hip/hip_runtime.h>

// Problem constants
#define BB 2048
#define TT 26
#define DIN 512
#define HH 512
#define EE 256
#define CC 97
#define SS 32
#define XK 1280   // DIN + EE + HH (fused LSTM input width)
#define G4 2048   // 4*H

typedef unsigned short u16;
typedef __bf16 bf16x8 __attribute__((ext_vector_type(8)));
typedef float f32x4 __attribute__((ext_vector_type(4)));

__device__ __forceinline__ float bf2f(u16 u) {
    return __uint_as_float(((unsigned int)u) << 16);
}
__device__ __forceinline__ u16 f2bf(float f) {  // round-to-nearest-even
    unsigned int u = __float_as_uint(f);
    u = u + 0x7FFFu + ((u >> 16) & 1u);
    return (u16)(u >> 16);
}
__device__ __forceinline__ float sigmoidf(float x) { return 1.0f / (1.0f + expf(-x)); }

// async global->LDS, 16B per lane; dst must be wave-uniform base (+lane*16 HW)
__device__ __forceinline__ void async16(const u16* g, u16* l) {
    __builtin_amdgcn_global_load_lds(
        (const __attribute__((address_space(1))) unsigned int*)(g),
        (__attribute__((address_space(3))) unsigned int*)(l), 16, 0, 0);
}

// ---------------------------------------------------------------------------
// gemm128: C[M,N] = A[M,K] @ W[N,K]^T (+ bias).  M%128==0, N%128==0, K%32==0.
// 128x128 tile / 256 threads; each wave computes a 64x64 quadrant via 4x4
// grid of 16x16x32 MFMAs.  global_load_lds width-16 staging (m97 structure).
// SWIZ: XCD-aware remap, valid only for a 16x16 grid.
// ---------------------------------------------------------------------------
template <bool OUT_BF16, bool BIAS, bool SWIZ>
__global__ __launch_bounds__(256) void gemm128(
    const u16* __restrict__ A, int lda,
    const u16* __restrict__ W,
    const float* __restrict__ bias,
    void* __restrict__ Cout, int ldc,
    int K)
{
    __shared__ __align__(16) u16 As[128 * 32];
    __shared__ __align__(16) u16 Ws[128 * 32];

    const int tid  = threadIdx.x;
    const int lane = tid & 63;
    const int wave = tid >> 6;

    int bx = blockIdx.x, by = blockIdx.y;
    if (SWIZ) {
        // 16x16 grid -> each XCD (b%8) walks a compact 4(y) x 8(x) region:
        // per-XCD L2 working set = 4 A-strips + 8 W-strips ~= 3.8 MB < 4 MB.
        int b   = by * gridDim.x + bx;
        int xcd = b & 7, loc = b >> 3;          // loc in [0,32)
        by = (xcd & 3) * 4 + (loc & 3);
        bx = (xcd >> 2) * 8 + (loc >> 2);
    }
    const int m0 = by * 128;
    const int n0 = bx * 128;

    // staging: 512 16B-chunks per operand; chunk c = row c>>2, k-quarter c&3.
    // thread t covers chunks t and t+256.
    const int srow = tid >> 2;            // 0..63
    const int scol = (tid & 3) * 8;       // u16 offset of 16B chunk in row
    const u16* Arow0 = A + (size_t)(m0 + srow) * lda + scol;
    const u16* Arow1 = A + (size_t)(m0 + 64 + srow) * lda + scol;
    const u16* Wrow0 = W + (size_t)(n0 + srow) * K + scol;
    const u16* Wrow1 = W + (size_t)(n0 + 64 + srow) * K + scol;
    u16* dstA0 = As + wave * 512;         // chunks [wave*64, wave*64+64)
    u16* dstA1 = As + 2048 + wave * 512;
    u16* dstW0 = Ws + wave * 512;
    u16* dstW1 = Ws + 2048 + wave * 512;

    const int wm = (wave >> 1) * 64;
    const int wn = (wave & 1) * 64;
    const int fr = lane & 15;
    const int fq = lane >> 4;

    f32x4 acc[4][4];
    #pragma unroll
    for (int i = 0; i < 4; i++)
        #pragma unroll
        for (int j = 0; j < 4; j++)
            #pragma unroll
            for (int r = 0; r < 4; r++) acc[i][j][r] = 0.0f;

    for (int k0 = 0; k0 < K; k0 += 32) {
        async16(Arow0 + k0, dstA0);
        async16(Arow1 + k0, dstA1);
        async16(Wrow0 + k0, dstW0);
        async16(Wrow1 + k0, dstW1);
        __syncthreads();

        bf16x8 af[4], bw[4];
        #pragma unroll
        for (int i = 0; i < 4; i++)
            af[i] = *(const bf16x8*)&As[(wm + i * 16 + fr) * 32 + fq * 8];
        #pragma unroll
        for (int j = 0; j < 4; j++)
            bw[j] = *(const bf16x8*)&Ws[(wn + j * 16 + fr) * 32 + fq * 8];
        #pragma unroll
        for (int i = 0; i < 4; i++)
            #pragma unroll
            for (int j = 0; j < 4; j++)
                acc[i][j] = __builtin_amdgcn_mfma_f32_16x16x32_bf16(
                    af[i], bw[j], acc[i][j], 0, 0, 0);
        __syncthreads();
    }

    // Epilogue: D col = lane&15, row = (lane>>4)*4 + r  (verified layout)
    #pragma unroll
    for (int j = 0; j < 4; j++) {
        int col = n0 + wn + j * 16 + fr;
        float bv = BIAS ? bias[col] : 0.0f;
        #pragma unroll
        for (int i = 0; i < 4; i++) {
            int row = m0 + wm + i * 16 + fq * 4;
            #pragma unroll
            for (int r = 0; r < 4; r++) {
                float v = acc[i][j][r] + bv;
                if (OUT_BF16)
                    ((u16*)Cout)[(size_t)(row + r) * ldc + col] = f2bf(v);
                else
                    ((float*)Cout)[(size_t)(row + r) * ldc + col] = v;
            }
        }
    }
}

// ---------------------------------------------------------------------------
// gemm_bt: 64x64-tile fallback for small-N GEMMs (ph: N=512, gen: N=97).
// ---------------------------------------------------------------------------
template <bool OUT_BF16, bool BIAS>
__global__ __launch_bounds__(256) void gemm_bt(
    const u16* __restrict__ A, int lda,
    const u16* __restrict__ W,
    const float* __restrict__ bias,
    void* __restrict__ Cout, int ldc,
    int N, int K)
{
    __shared__ __align__(16) u16 As[64][32];
    __shared__ __align__(16) u16 Ws[64][32];

    const int tid  = threadIdx.x;
    const int lane = tid & 63;
    const int wave = tid >> 6;
    const int m0 = blockIdx.y * 64;
    const int n0 = blockIdx.x * 64;
    const int ar = tid >> 2;
    const int ac = (tid & 3) * 8;
    const int wm = (wave >> 1) * 32;
    const int wn = (wave & 1) * 32;
    const int fr = lane & 15;
    const int fq = lane >> 4;

    f32x4 acc[2][2];
    #pragma unroll
    for (int i = 0; i < 2; i++)
        #pragma unroll
        for (int j = 0; j < 2; j++)
            #pragma unroll
            for (int r = 0; r < 4; r++) acc[i][j][r] = 0.0f;

    const bool wvalid = (n0 + ar) < N;
    const u16* Arow = A + (size_t)(m0 + ar) * lda;
    const u16* Wrow = W + (size_t)(n0 + ar) * K;

    for (int k0 = 0; k0 < K; k0 += 32) {
        uint4 av = *(const uint4*)(Arow + k0 + ac);
        uint4 wv = make_uint4(0u, 0u, 0u, 0u);
        if (wvalid) wv = *(const uint4*)(Wrow + k0 + ac);
        *(uint4*)&As[ar][ac] = av;
        *(uint4*)&Ws[ar][ac] = wv;
        __syncthreads();

        bf16x8 af[2], bfr[2];
        #pragma unroll
        for (int mm = 0; mm < 2; mm++)
            af[mm] = *(const bf16x8*)&As[wm + mm * 16 + fr][fq * 8];
        #pragma unroll
        for (int nn = 0; nn < 2; nn++)
            bfr[nn] = *(const bf16x8*)&Ws[wn + nn * 16 + fr][fq * 8];
        #pragma unroll
        for (int mm = 0; mm < 2; mm++)
            #pragma unroll
            for (int nn = 0; nn < 2; nn++)
                acc[mm][nn] = __builtin_amdgcn_mfma_f32_16x16x32_bf16(
                    af[mm], bfr[nn], acc[mm][nn], 0, 0, 0);
        __syncthreads();
    }

    #pragma unroll
    for (int nn = 0; nn < 2; nn++) {
        int col = n0 + wn + nn * 16 + fr;
        if (col < N) {
            float bv = BIAS ? bias[col] : 0.0f;
            #pragma unroll
            for (int mm = 0; mm < 2; mm++) {
                int row = m0 + wm + mm * 16 + fq * 4;
                #pragma unroll
                for (int r = 0; r < 4; r++) {
                    float v = acc[mm][nn][r] + bv;
                    if (OUT_BF16)
                        ((u16*)Cout)[(size_t)(row + r) * ldc + col] = f2bf(v);
                    else
                        ((float*)Cout)[(size_t)(row + r) * ldc + col] = v;
                }
            }
        }
    }
}

// ---------------------------------------------------------------------------
// fp32 -> bf16 cast, 4 elements/thread (n divisible by 4)
// ---------------------------------------------------------------------------
__global__ __launch_bounds__(256) void cast_f32_bf16(
    const float* __restrict__ src, u16* __restrict__ dst, int n)
{
    int i = (blockIdx.x * 256 + threadIdx.x) * 4;
    if (i < n) {
        float4 v = *(const float4*)(src + i);
        ushort4 o;
        o.x = f2bf(v.x); o.y = f2bf(v.y); o.z = f2bf(v.z); o.w = f2bf(v.w);
        *(ushort4*)(dst + i) = o;
    }
}

// ---------------------------------------------------------------------------
// Build Wcat[n][k] = bf16([W_ih | W_hh]) and bcat = b_ih + b_hh (fp32)
// ---------------------------------------------------------------------------
__global__ __launch_bounds__(256) void build_wcat(
    const float* __restrict__ W_ih, const float* __restrict__ W_hh,
    const float* __restrict__ b_ih, const float* __restrict__ b_hh,
    u16* __restrict__ Wcat, float* __restrict__ bcat)
{
    int i = blockIdx.x * 256 + threadIdx.x;
    if (i < G4 * XK) {
        int n = i / XK, k = i - n * XK;
        float v = (k < DIN + EE) ? W_ih[(size_t)n * (DIN + EE) + k]
                                 : W_hh[(size_t)n * HH + (k - DIN - EE)];
        Wcat[(size_t)i] = f2bf(v);
    }
    if (i < G4) bcat[i] = b_ih[i] + b_hh[i];
}

// Init: c = 0 (fp32), h-region of x' = 0 (bf16 bits)
__global__ __launch_bounds__(256) void init_state(float* __restrict__ c,
                                                  u16* __restrict__ xp)
{
    int i = blockIdx.x * 256 + threadIdx.x;  // < B*H
    if (i < BB * HH) {
        c[i] = 0.0f;
        int b = i >> 9, h = i & (HH - 1);
        xp[(size_t)b * XK + DIN + EE + h] = 0;
    }
}

// ---------------------------------------------------------------------------
// Attention step (one 256-thread block per batch row)
// ---------------------------------------------------------------------------
__global__ __launch_bounds__(256) void attn_step(
    const u16* __restrict__ Hp, const float* __restrict__ ph,
    const float* __restrict__ wscore, const u16* __restrict__ bH16,
    const int* __restrict__ text, const float* __restrict__ emb,
    u16* __restrict__ xp, int s)
{
    const int b = blockIdx.x;
    const int tid = threadIdx.x, lane = tid & 63, wave = tid >> 6;
    __shared__ float e_sm[TT];
    __shared__ float alpha_sm[TT];

    const float* phb = ph + (size_t)b * HH;
    for (int t = wave; t < TT; t += 4) {
        const u16* hp = Hp + ((size_t)b * TT + t) * HH;
        float sum = 0.0f;
        for (int h = lane; h < HH; h += 64)
            sum += tanhf(bf2f(hp[h]) + phb[h]) * wscore[h];
        #pragma unroll
        for (int off = 32; off > 0; off >>= 1) sum += __shfl_down(sum, off);
        if (lane == 0) e_sm[t] = sum;
    }
    __syncthreads();

    if (tid == 0) {
        float mx = e_sm[0];
        for (int t = 1; t < TT; t++) mx = fmaxf(mx, e_sm[t]);
        float ssum = 0.0f;
        for (int t = 0; t < TT; t++) {
            float ev = expf(e_sm[t] - mx);
            alpha_sm[t] = ev;
            ssum += ev;
        }
        float inv = 1.0f / ssum;
        for (int t = 0; t < TT; t++) alpha_sm[t] *= inv;
    }
    __syncthreads();

    for (int d = tid; d < DIN; d += 256) {
        float ctx = 0.0f;
        const u16* bh = bH16 + (size_t)b * TT * DIN + d;
        #pragma unroll
        for (int t = 0; t < TT; t++) ctx += alpha_sm[t] * bf2f(bh[(size_t)t * DIN]);
        xp[(size_t)b * XK + d] = f2bf(ctx);
    }

    int ch = text[b * SS + s];
    const float* e = emb + (size_t)ch * EE;
    for (int j = tid; j < EE; j += 256)
        xp[(size_t)b * XK + DIN + j] = f2bf(e[j]);
}

// ---------------------------------------------------------------------------
// LSTM pointwise: gate order i,f,g,o.  c fp32 persistent; h -> bf16 into x'.
// ---------------------------------------------------------------------------
__global__ __launch_bounds__(256) void lstm_cell(
    const float* __restrict__ gates, float* __restrict__ c,
    u16* __restrict__ xp)
{
    int i = blockIdx.x * 256 + threadIdx.x;  // < B*H
    int b = i >> 9, h = i & (HH - 1);
    const float* g = gates + (size_t)b * G4;
    float ig = sigmoidf(g[h]);
    float fg = sigmoidf(g[HH + h]);
    float gg = tanhf(g[2 * HH + h]);
    float og = sigmoidf(g[3 * HH + h]);
    float cn = fg * c[i] + ig * gg;
    c[i] = cn;
    float hn = og * tanhf(cn);
    xp[(size_t)b * XK + DIN + EE + h] = f2bf(hn);
}

// ---------------------------------------------------------------------------
// Workspace layout (bytes)
// ---------------------------------------------------------------------------
#define BH16_OFF   ((size_t)0)                       // bf16 [B*T, DIN]  54,525,952
#define HP_OFF     ((size_t)54525952)                // bf16 [B*T, H]    54,525,952
#define XP_OFF     ((size_t)109051904)               // bf16 [B, 1280]    5,242,880
#define WCAT_OFF   ((size_t)114294784)               // bf16 [2048,1280]  5,242,880
#define WI2H_OFF   ((size_t)119537664)               // bf16 [512,512]      524,288
#define WH2H_OFF   ((size_t)120061952)               // bf16 [512,512]      524,288
#define WGEN_OFF   ((size_t)120586240)               // bf16 [97,512]pad    131,072
#define BCAT_OFF   ((size_t)120717312)               // f32 [2048]            8,192
#define PH_OFF     ((size_t)120725504)               // f32 [B,512]       4,194,304
#define GATES_OFF  ((size_t)124919808)               // f32 [B,2048]     16,777,216
#define CST_OFF    ((size_t)141697024)               // f32 [B,512]       4,194,304
// total ~145.9 MB

extern "C" void kernel_launch(void* const* d_in, const int* in_sizes, int n_in,
                              void* d_out, int out_size, void* d_ws, size_t ws_size,
                              hipStream_t stream)
{
    const float* batch_H = (const float*)d_in[0];
    const int*   text    = (const int*)d_in[1];
    const float* W_i2h   = (const float*)d_in[2];
    const float* W_h2h   = (const float*)d_in[3];
    const float* b_h2h   = (const float*)d_in[4];
    const float* w_score = (const float*)d_in[5];
    const float* W_ih    = (const float*)d_in[6];
    const float* W_hh    = (const float*)d_in[7];
    const float* b_ih    = (const float*)d_in[8];
    const float* b_hh    = (const float*)d_in[9];
    const float* W_gen   = (const float*)d_in[10];
    const float* b_gen   = (const float*)d_in[11];
    const float* emb     = (const float*)d_in[12];

    char* ws = (char*)d_ws;
    u16*   bH16   = (u16*)(ws + BH16_OFF);
    u16*   Hp     = (u16*)(ws + HP_OFF);
    u16*   xp     = (u16*)(ws + XP_OFF);
    u16*   Wcat   = (u16*)(ws + WCAT_OFF);
    u16*   Wi2h16 = (u16*)(ws + WI2H_OFF);
    u16*   Wh2h16 = (u16*)(ws + WH2H_OFF);
    u16*   Wgen16 = (u16*)(ws + WGEN_OFF);
    float* bcat   = (float*)(ws + BCAT_OFF);
    float* ph     = (float*)(ws + PH_OFF);
    float* gates  = (float*)(ws + GATES_OFF);
    float* cst    = (float*)(ws + CST_OFF);
    float* out    = (float*)d_out;

    // One-time prep: casts + fused weight build + state init
    cast_f32_bf16<<<dim3((BB * TT * DIN / 4 + 255) / 256), 256, 0, stream>>>(
        batch_H, bH16, BB * TT * DIN);
    cast_f32_bf16<<<dim3((HH * DIN / 4 + 255) / 256), 256, 0, stream>>>(
        W_i2h, Wi2h16, HH * DIN);
    cast_f32_bf16<<<dim3((HH * HH / 4 + 255) / 256), 256, 0, stream>>>(
        W_h2h, Wh2h16, HH * HH);
    cast_f32_bf16<<<dim3((CC * HH / 4 + 255) / 256), 256, 0, stream>>>(
        W_gen, Wgen16, CC * HH);
    build_wcat<<<dim3((G4 * XK + 255) / 256), 256, 0, stream>>>(
        W_ih, W_hh, b_ih, b_hh, Wcat, bcat);
    init_state<<<dim3((BB * HH + 255) / 256), 256, 0, stream>>>(cst, xp);

    // Hp = batch_H @ W_i2h^T   [B*T, H] bf16   (128-tile MFMA)
    gemm128<true, false, false><<<dim3(HH / 128, (BB * TT) / 128), 256, 0, stream>>>(
        bH16, DIN, Wi2h16, nullptr, Hp, HH, DIN);

    for (int s = 0; s < SS; s++) {
        // ph = h @ W_h2h^T + b_h2h   (fp32)
        gemm_bt<false, true><<<dim3(HH / 64, BB / 64), 256, 0, stream>>>(
            xp + DIN + EE, XK, Wh2h16, b_h2h, ph, HH, HH, HH);

        // attention -> context & char-embedding into x'
        attn_step<<<dim3(BB), 256, 0, stream>>>(Hp, ph, w_score, bH16,
                                                text, emb, xp, s);

        // gates = [context|ce|h] @ [W_ih|W_hh]^T + (b_ih+b_hh)  (128-tile, swizzled)
        gemm128<false, true, true><<<dim3(G4 / 128, BB / 128), 256, 0, stream>>>(
            xp, XK, Wcat, bcat, gates, G4, XK);

        // LSTM pointwise; h (bf16) back into x'
        lstm_cell<<<dim3((BB * HH + 255) / 256), 256, 0, stream>>>(gates, cst, xp);

        // probs[:, s, :] = h @ W_gen^T + b_gen  (fp32, strided into [B,S,C])
        gemm_bt<false, true><<<dim3((CC + 63) / 64, BB / 64), 256, 0, stream>>>(
            xp + DIN + EE, XK, Wgen16, b_gen, out + (size_t)s * CC, SS * CC, CC, HH);
    }
}

// Round 4
// 1987.213 us; speedup vs baseline: 1.8186x; 1.8186x over previous
//
#include <hip/hip_runtime.h>

// Problem constants
#define BB 2048
#define TT 26
#define DIN 512
#define HH 512
#define EE 256
#define CC 97
#define SS 32
#define XK 1280   // DIN + EE + HH
#define G4 2048   // 4*H
#define NPG 640   // 512 (ph) + 97 (gen) padded

typedef unsigned short u16;
typedef __bf16 bf16x8 __attribute__((ext_vector_type(8)));
typedef float f32x4 __attribute__((ext_vector_type(4)));

__device__ __forceinline__ float bf2f(u16 u) {
    return __uint_as_float(((unsigned int)u) << 16);
}
__device__ __forceinline__ u16 f2bf(float f) {  // RNE
    unsigned int u = __float_as_uint(f);
    u = u + 0x7FFFu + ((u >> 16) & 1u);
    return (u16)(u >> 16);
}
// fast tanh/sigmoid: v_exp_f32 + v_rcp_f32 (err << bf16 rounding)
__device__ __forceinline__ float th_f(float x) {
    return 1.0f - 2.0f * __builtin_amdgcn_rcpf(__expf(2.0f * x) + 1.0f);
}
__device__ __forceinline__ float sig_f(float x) {
    return __builtin_amdgcn_rcpf(1.0f + __expf(-x));
}

// async global->LDS, 16B/lane; LDS base wave-uniform
__device__ __forceinline__ void async16(const u16* g, u16* l) {
    __builtin_amdgcn_global_load_lds(
        (const __attribute__((address_space(1))) unsigned int*)(g),
        (__attribute__((address_space(3))) unsigned int*)(l), 16, 0, 0);
}

// ---------------------------------------------------------------------------
// gemm128 (Hp only): C[M,N] = A[M,K] @ W[N,K]^T, 128x128 tile, m97 staging.
// ---------------------------------------------------------------------------
__global__ __launch_bounds__(256) void gemm128(
    const u16* __restrict__ A, int lda,
    const u16* __restrict__ W,
    u16* __restrict__ Cout, int ldc, int K)
{
    __shared__ __align__(16) u16 As[128 * 32];
    __shared__ __align__(16) u16 Ws[128 * 32];

    const int tid  = threadIdx.x;
    const int lane = tid & 63;
    const int wave = tid >> 6;
    const int m0 = blockIdx.y * 128;
    const int n0 = blockIdx.x * 128;

    const int srow = tid >> 2;
    const int scol = (tid & 3) * 8;
    const u16* Arow0 = A + (size_t)(m0 + srow) * lda + scol;
    const u16* Arow1 = A + (size_t)(m0 + 64 + srow) * lda + scol;
    const u16* Wrow0 = W + (size_t)(n0 + srow) * K + scol;
    const u16* Wrow1 = W + (size_t)(n0 + 64 + srow) * K + scol;
    u16* dstA0 = As + wave * 512;
    u16* dstA1 = As + 2048 + wave * 512;
    u16* dstW0 = Ws + wave * 512;
    u16* dstW1 = Ws + 2048 + wave * 512;

    const int wm = (wave >> 1) * 64;
    const int wn = (wave & 1) * 64;
    const int fr = lane & 15;
    const int fq = lane >> 4;

    f32x4 acc[4][4];
    #pragma unroll
    for (int i = 0; i < 4; i++)
        #pragma unroll
        for (int j = 0; j < 4; j++)
            #pragma unroll
            for (int r = 0; r < 4; r++) acc[i][j][r] = 0.0f;

    for (int k0 = 0; k0 < K; k0 += 32) {
        async16(Arow0 + k0, dstA0);
        async16(Arow1 + k0, dstA1);
        async16(Wrow0 + k0, dstW0);
        async16(Wrow1 + k0, dstW1);
        __syncthreads();
        bf16x8 af[4], bw[4];
        #pragma unroll
        for (int i = 0; i < 4; i++)
            af[i] = *(const bf16x8*)&As[(wm + i * 16 + fr) * 32 + fq * 8];
        #pragma unroll
        for (int j = 0; j < 4; j++)
            bw[j] = *(const bf16x8*)&Ws[(wn + j * 16 + fr) * 32 + fq * 8];
        #pragma unroll
        for (int i = 0; i < 4; i++)
            #pragma unroll
            for (int j = 0; j < 4; j++)
                acc[i][j] = __builtin_amdgcn_mfma_f32_16x16x32_bf16(
                    af[i], bw[j], acc[i][j], 0, 0, 0);
        __syncthreads();
    }

    #pragma unroll
    for (int j = 0; j < 4; j++) {
        int col = n0 + wn + j * 16 + fr;
        #pragma unroll
        for (int i = 0; i < 4; i++) {
            int row = m0 + wm + i * 16 + fq * 4;
            #pragma unroll
            for (int r = 0; r < 4; r++)
                Cout[(size_t)(row + r) * ldc + col] = f2bf(acc[i][j][r]);
        }
    }
}

// ---------------------------------------------------------------------------
// gates_lstm: gates = X @ Wcat^T + bcat (interleaved col = 4h+gate), then
// LSTM cell fused in epilogue.  Tile 64(M)x128(N), grid (16,16*2)=512 blocks
// -> 2 blocks/CU.  h_{s+1} -> xn (ping-pong buffer).
// ---------------------------------------------------------------------------
__global__ __launch_bounds__(256) void gates_lstm(
    const u16* __restrict__ X,      // [B][XK] current step input
    const u16* __restrict__ Wc,     // [2048][1280] interleaved
    const float* __restrict__ bias, // [2048] interleaved
    float* __restrict__ c,          // [B][512]
    u16* __restrict__ xn)           // next-step buffer (h at +768)
{
    __shared__ __align__(16) u16 As[64 * 32];    // 4 KB
    __shared__ __align__(16) u16 Ws[128 * 32];   // 8 KB
    __shared__ float gsm[64 * 68];               // 17 KB (pass-sliced)

    const int tid  = threadIdx.x;
    const int lane = tid & 63;
    const int wave = tid >> 6;

    // XCD swizzle: grid (x=16,y=32); per-XCD 8x8 region (3.84 MB < 4 MB L2)
    int b   = blockIdx.y * gridDim.x + blockIdx.x;
    int xcd = b & 7, loc = b >> 3;
    int by = (xcd & 3) * 8 + (loc & 7);     // 0..31  (M tiles)
    int bx = (xcd >> 2) * 8 + (loc >> 3);   // 0..15  (N tiles)
    const int m0 = by * 64;
    const int n0 = bx * 128;

    const int srow = tid >> 2;
    const int scol = (tid & 3) * 8;
    const u16* Arow  = X  + (size_t)(m0 + srow) * XK + scol;
    const u16* Wrow0 = Wc + (size_t)(n0 + srow) * XK + scol;
    const u16* Wrow1 = Wc + (size_t)(n0 + 64 + srow) * XK + scol;
    u16* dstA  = As + wave * 512;
    u16* dstW0 = Ws + wave * 512;
    u16* dstW1 = Ws + 2048 + wave * 512;

    const int wm = (wave & 1) * 32;   // 2x2 wave grid: 32M x 64N each
    const int wn = (wave >> 1) * 64;
    const int fr = lane & 15;
    const int fq = lane >> 4;

    f32x4 acc[2][4];
    #pragma unroll
    for (int i = 0; i < 2; i++)
        #pragma unroll
        for (int j = 0; j < 4; j++)
            #pragma unroll
            for (int r = 0; r < 4; r++) acc[i][j][r] = 0.0f;

    for (int k0 = 0; k0 < XK; k0 += 32) {
        async16(Arow + k0, dstA);
        async16(Wrow0 + k0, dstW0);
        async16(Wrow1 + k0, dstW1);
        __syncthreads();
        bf16x8 af[2], bw[4];
        #pragma unroll
        for (int i = 0; i < 2; i++)
            af[i] = *(const bf16x8*)&As[(wm + i * 16 + fr) * 32 + fq * 8];
        #pragma unroll
        for (int j = 0; j < 4; j++)
            bw[j] = *(const bf16x8*)&Ws[(wn + j * 16 + fr) * 32 + fq * 8];
        #pragma unroll
        for (int i = 0; i < 2; i++)
            #pragma unroll
            for (int j = 0; j < 4; j++)
                acc[i][j] = __builtin_amdgcn_mfma_f32_16x16x32_bf16(
                    af[i], bw[j], acc[i][j], 0, 0, 0);
        __syncthreads();
    }

    // Epilogue in two 64-col passes: stage to LDS (+bias), fused LSTM.
    #pragma unroll
    for (int p = 0; p < 2; p++) {
        if ((wave >> 1) == p) {
            #pragma unroll
            for (int j = 0; j < 4; j++) {
                int cl = j * 16 + fr;                       // 0..63 local col
                float bv = bias[n0 + p * 64 + cl];
                #pragma unroll
                for (int i = 0; i < 2; i++) {
                    int rl = wm + i * 16 + fq * 4;
                    #pragma unroll
                    for (int r = 0; r < 4; r++)
                        gsm[(rl + r) * 68 + cl] = acc[i][j][r] + bv;
                }
            }
        }
        __syncthreads();
        // 64 rows x 16 h-units = 1024 cells
        #pragma unroll
        for (int rr = 0; rr < 4; rr++) {
            int idx = rr * 256 + tid;
            int u = idx & 15, row = idx >> 4;
            int base = row * 68 + 4 * u;
            float ig = sig_f(gsm[base]);
            float fg = sig_f(gsm[base + 1]);
            float gg = th_f(gsm[base + 2]);
            float og = sig_f(gsm[base + 3]);
            int hg = (n0 >> 2) + p * 16 + u;
            size_t ci = (size_t)(m0 + row) * HH + hg;
            float cn = fg * c[ci] + ig * gg;
            c[ci] = cn;
            xn[(size_t)(m0 + row) * XK + DIN + EE + hg] = f2bf(og * th_f(cn));
        }
        __syncthreads();
    }
}

// ---------------------------------------------------------------------------
// phgen: [ph | probs_s] = h @ [W_h2h; W_gen]^T + [b_h2h; b_gen]
// 64x64 tile, N=640, K=512.  grid (10, 32).
// ---------------------------------------------------------------------------
__global__ __launch_bounds__(256) void phgen(
    const u16* __restrict__ A,      // h rows: xn + 768, lda XK
    const u16* __restrict__ W,      // [640][512]
    const float* __restrict__ bias, // [640]
    float* __restrict__ ph, float* __restrict__ out, int s)
{
    __shared__ __align__(16) u16 As[64][32];
    __shared__ __align__(16) u16 Ws[64][32];

    const int tid  = threadIdx.x;
    const int lane = tid & 63;
    const int wave = tid >> 6;
    const int m0 = blockIdx.y * 64;
    const int n0 = blockIdx.x * 64;
    const int ar = tid >> 2;
    const int ac = (tid & 3) * 8;
    const int wm = (wave >> 1) * 32;
    const int wn = (wave & 1) * 32;
    const int fr = lane & 15;
    const int fq = lane >> 4;

    f32x4 acc[2][2];
    #pragma unroll
    for (int i = 0; i < 2; i++)
        #pragma unroll
        for (int j = 0; j < 2; j++)
            #pragma unroll
            for (int r = 0; r < 4; r++) acc[i][j][r] = 0.0f;

    const u16* Arow = A + (size_t)(m0 + ar) * XK;
    const u16* Wrow = W + (size_t)(n0 + ar) * HH;

    for (int k0 = 0; k0 < HH; k0 += 32) {
        uint4 av = *(const uint4*)(Arow + k0 + ac);
        uint4 wv = *(const uint4*)(Wrow + k0 + ac);
        *(uint4*)&As[ar][ac] = av;
        *(uint4*)&Ws[ar][ac] = wv;
        __syncthreads();
        bf16x8 af[2], bw[2];
        #pragma unroll
        for (int mm = 0; mm < 2; mm++)
            af[mm] = *(const bf16x8*)&As[wm + mm * 16 + fr][fq * 8];
        #pragma unroll
        for (int nn = 0; nn < 2; nn++)
            bw[nn] = *(const bf16x8*)&Ws[wn + nn * 16 + fr][fq * 8];
        #pragma unroll
        for (int mm = 0; mm < 2; mm++)
            #pragma unroll
            for (int nn = 0; nn < 2; nn++)
                acc[mm][nn] = __builtin_amdgcn_mfma_f32_16x16x32_bf16(
                    af[mm], bw[nn], acc[mm][nn], 0, 0, 0);
        __syncthreads();
    }

    #pragma unroll
    for (int nn = 0; nn < 2; nn++) {
        int col = n0 + wn + nn * 16 + fr;
        float bv = bias[col];
        #pragma unroll
        for (int mm = 0; mm < 2; mm++) {
            int row = m0 + wm + mm * 16 + fq * 4;
            #pragma unroll
            for (int r = 0; r < 4; r++) {
                float v = acc[mm][nn][r] + bv;
                if (col < HH)
                    ph[(size_t)(row + r) * HH + col] = v;
                else if (col < HH + CC)
                    out[(size_t)(row + r) * (SS * CC) + s * CC + (col - HH)] = v;
            }
        }
    }
}

// ---------------------------------------------------------------------------
// attn_step: e/softmax/context + char-embedding into xc.  1 block / row.
// ---------------------------------------------------------------------------
__global__ __launch_bounds__(256) void attn_step(
    const u16* __restrict__ Hp, const float* __restrict__ ph,
    const float* __restrict__ wscore, const u16* __restrict__ bH16,
    const int* __restrict__ text, const float* __restrict__ emb,
    u16* __restrict__ xc, int s)
{
    const int b = blockIdx.x;
    const int tid = threadIdx.x, lane = tid & 63, wave = tid >> 6;
    __shared__ float e_sm[32];
    __shared__ float alpha_sm[32];

    // hoisted per-lane 8-wide slices of ph and w_score
    const int h8 = lane * 8;
    float ph_r[8], ws_r[8];
    {
        float4 p0 = *(const float4*)(ph + (size_t)b * HH + h8);
        float4 p1 = *(const float4*)(ph + (size_t)b * HH + h8 + 4);
        ph_r[0]=p0.x; ph_r[1]=p0.y; ph_r[2]=p0.z; ph_r[3]=p0.w;
        ph_r[4]=p1.x; ph_r[5]=p1.y; ph_r[6]=p1.z; ph_r[7]=p1.w;
        float4 w0 = *(const float4*)(wscore + h8);
        float4 w1 = *(const float4*)(wscore + h8 + 4);
        ws_r[0]=w0.x; ws_r[1]=w0.y; ws_r[2]=w0.z; ws_r[3]=w0.w;
        ws_r[4]=w1.x; ws_r[5]=w1.y; ws_r[6]=w1.z; ws_r[7]=w1.w;
    }

    for (int t = wave; t < TT; t += 4) {
        uint4 hv = *(const uint4*)(Hp + ((size_t)b * TT + t) * HH + h8);
        const u16* hu = (const u16*)&hv;
        float sum = 0.0f;
        #pragma unroll
        for (int j = 0; j < 8; j++)
            sum += th_f(bf2f(hu[j]) + ph_r[j]) * ws_r[j];
        #pragma unroll
        for (int off = 32; off > 0; off >>= 1) sum += __shfl_down(sum, off);
        if (lane == 0) e_sm[t] = sum;
    }
    __syncthreads();

    if (tid == 0) {
        float mx = e_sm[0];
        for (int t = 1; t < TT; t++) mx = fmaxf(mx, e_sm[t]);
        float ssum = 0.0f;
        for (int t = 0; t < TT; t++) {
            float ev = __expf(e_sm[t] - mx);
            alpha_sm[t] = ev;
            ssum += ev;
        }
        float inv = 1.0f / ssum;
        for (int t = 0; t < TT; t++) alpha_sm[t] *= inv;
    }
    __syncthreads();

    // context: 2 d per thread
    {
        int d0 = tid * 2;
        float c0 = 0.0f, c1 = 0.0f;
        const u16* bb = bH16 + (size_t)b * TT * DIN + d0;
        #pragma unroll
        for (int t = 0; t < TT; t++) {
            unsigned int v = *(const unsigned int*)(bb + (size_t)t * DIN);
            float a = alpha_sm[t];
            c0 += a * bf2f((u16)(v & 0xffffu));
            c1 += a * bf2f((u16)(v >> 16));
        }
        unsigned int o = (unsigned int)f2bf(c0) | ((unsigned int)f2bf(c1) << 16);
        *(unsigned int*)(xc + (size_t)b * XK + d0) = o;
    }

    // char embedding
    if (tid < 64) {
        int ch = text[b * SS + s];
        float4 e4 = *(const float4*)(emb + (size_t)ch * EE + tid * 4);
        uint2 o;
        o.x = (unsigned int)f2bf(e4.x) | ((unsigned int)f2bf(e4.y) << 16);
        o.y = (unsigned int)f2bf(e4.z) | ((unsigned int)f2bf(e4.w) << 16);
        *(uint2*)(xc + (size_t)b * XK + DIN + tid * 4) = o;
    }
}

// ---------------------------------------------------------------------------
// prep kernels
// ---------------------------------------------------------------------------
__global__ __launch_bounds__(256) void cast_f32_bf16(
    const float* __restrict__ src, u16* __restrict__ dst, int n)
{
    int i = (blockIdx.x * 256 + threadIdx.x) * 4;
    if (i < n) {
        float4 v = *(const float4*)(src + i);
        ushort4 o;
        o.x = f2bf(v.x); o.y = f2bf(v.y); o.z = f2bf(v.z); o.w = f2bf(v.w);
        *(ushort4*)(dst + i) = o;
    }
}

// Wcat interleaved: row n' = 4h+g  <-  orig row n = g*512+h.
__global__ __launch_bounds__(256) void build_wcat(
    const float* __restrict__ W_ih, const float* __restrict__ W_hh,
    const float* __restrict__ b_ih, const float* __restrict__ b_hh,
    u16* __restrict__ Wcat, float* __restrict__ bcat)
{
    int i = blockIdx.x * 256 + threadIdx.x;
    if (i < G4 * XK) {
        int np = i / XK, k = i - np * XK;
        int h = np >> 2, g = np & 3;
        int n = g * HH + h;
        float v = (k < DIN + EE) ? W_ih[(size_t)n * (DIN + EE) + k]
                                 : W_hh[(size_t)n * HH + (k - DIN - EE)];
        Wcat[(size_t)i] = f2bf(v);
    }
    if (i < G4) {
        int h = i >> 2, g = i & 3;
        int n = g * HH + h;
        bcat[i] = b_ih[n] + b_hh[n];
    }
}

// Wpg = bf16([W_h2h ; W_gen ; 0]), bpg = [b_h2h ; b_gen ; 0]
__global__ __launch_bounds__(256) void build_wpg(
    const float* __restrict__ W_h2h, const float* __restrict__ W_gen,
    const float* __restrict__ b_h2h, const float* __restrict__ b_gen,
    u16* __restrict__ Wpg, float* __restrict__ bpg)
{
    int i = blockIdx.x * 256 + threadIdx.x;
    if (i < NPG * HH) {
        int n = i >> 9, k = i & (HH - 1);
        float v = (n < HH) ? W_h2h[(size_t)n * HH + k]
                 : (n < HH + CC) ? W_gen[(size_t)(n - HH) * HH + k] : 0.0f;
        Wpg[(size_t)i] = f2bf(v);
    }
    if (i < NPG)
        bpg[i] = (i < HH) ? b_h2h[i] : (i < HH + CC) ? b_gen[i - HH] : 0.0f;
}

// c = 0, h-region of xp0 = 0, ph = b_h2h (h0 = 0)
__global__ __launch_bounds__(256) void init_state(
    float* __restrict__ c, u16* __restrict__ xp0,
    float* __restrict__ ph, const float* __restrict__ b_h2h)
{
    int i = blockIdx.x * 256 + threadIdx.x;  // < B*H
    if (i < BB * HH) {
        c[i] = 0.0f;
        int b = i >> 9, h = i & (HH - 1);
        xp0[(size_t)b * XK + DIN + EE + h] = 0;
        ph[i] = b_h2h[h];
    }
}

// ---------------------------------------------------------------------------
// Workspace layout (bytes)
// ---------------------------------------------------------------------------
#define BH16_OFF ((size_t)0)            // bf16 [B*T, DIN]   54,525,952
#define HP_OFF   ((size_t)54525952)     // bf16 [B*T, H]     54,525,952
#define XP0_OFF  ((size_t)109051904)    // bf16 [B, 1280]     5,242,880
#define XP1_OFF  ((size_t)114294784)    // bf16 [B, 1280]     5,242,880
#define WCAT_OFF ((size_t)119537664)    // bf16 [2048,1280]   5,242,880
#define WI2H_OFF ((size_t)124780544)    // bf16 [512,512]       524,288
#define WPG_OFF  ((size_t)125304832)    // bf16 [640,512]       655,360
#define BCAT_OFF ((size_t)125960192)    // f32 [2048]             8,192
#define BPG_OFF  ((size_t)125968384)    // f32 [640]              2,560
#define PH_OFF   ((size_t)125971456)    // f32 [B,512]        4,194,304
#define CST_OFF  ((size_t)130165760)    // f32 [B,512]        4,194,304
// total ~134.4 MB

extern "C" void kernel_launch(void* const* d_in, const int* in_sizes, int n_in,
                              void* d_out, int out_size, void* d_ws, size_t ws_size,
                              hipStream_t stream)
{
    const float* batch_H = (const float*)d_in[0];
    const int*   text    = (const int*)d_in[1];
    const float* W_i2h   = (const float*)d_in[2];
    const float* W_h2h   = (const float*)d_in[3];
    const float* b_h2h   = (const float*)d_in[4];
    const float* w_score = (const float*)d_in[5];
    const float* W_ih    = (const float*)d_in[6];
    const float* W_hh    = (const float*)d_in[7];
    const float* b_ih    = (const float*)d_in[8];
    const float* b_hh    = (const float*)d_in[9];
    const float* W_gen   = (const float*)d_in[10];
    const float* b_gen   = (const float*)d_in[11];
    const float* emb     = (const float*)d_in[12];

    char* ws = (char*)d_ws;
    u16*   bH16   = (u16*)(ws + BH16_OFF);
    u16*   Hp     = (u16*)(ws + HP_OFF);
    u16*   xp0    = (u16*)(ws + XP0_OFF);
    u16*   xp1    = (u16*)(ws + XP1_OFF);
    u16*   Wcat   = (u16*)(ws + WCAT_OFF);
    u16*   Wi2h16 = (u16*)(ws + WI2H_OFF);
    u16*   Wpg    = (u16*)(ws + WPG_OFF);
    float* bcat   = (float*)(ws + BCAT_OFF);
    float* bpg    = (float*)(ws + BPG_OFF);
    float* ph     = (float*)(ws + PH_OFF);
    float* cst    = (float*)(ws + CST_OFF);
    float* out    = (float*)d_out;

    // prep
    cast_f32_bf16<<<dim3((BB * TT * DIN / 4 + 255) / 256), 256, 0, stream>>>(
        batch_H, bH16, BB * TT * DIN);
    cast_f32_bf16<<<dim3((HH * DIN / 4 + 255) / 256), 256, 0, stream>>>(
        W_i2h, Wi2h16, HH * DIN);
    build_wcat<<<dim3((G4 * XK + 255) / 256), 256, 0, stream>>>(
        W_ih, W_hh, b_ih, b_hh, Wcat, bcat);
    build_wpg<<<dim3((NPG * HH + 255) / 256), 256, 0, stream>>>(
        W_h2h, W_gen, b_h2h, b_gen, Wpg, bpg);
    init_state<<<dim3((BB * HH + 255) / 256), 256, 0, stream>>>(
        cst, xp0, ph, b_h2h);

    // Hp = batch_H @ W_i2h^T
    gemm128<<<dim3(HH / 128, (BB * TT) / 128), 256, 0, stream>>>(
        bH16, DIN, Wi2h16, Hp, HH, DIN);

    for (int s = 0; s < SS; s++) {
        u16* xc = (s & 1) ? xp1 : xp0;   // holds ctx|ce|h_s
        u16* xn = (s & 1) ? xp0 : xp1;   // receives h_{s+1}

        attn_step<<<dim3(BB), 256, 0, stream>>>(Hp, ph, w_score, bH16,
                                                text, emb, xc, s);

        gates_lstm<<<dim3(G4 / 128, BB / 64), 256, 0, stream>>>(
            xc, Wcat, bcat, cst, xn);

        phgen<<<dim3(NPG / 64, BB / 64), 256, 0, stream>>>(
            xn + DIN + EE, Wpg, bpg, ph, out, s);
    }
}

// Round 5
// 1817.680 us; speedup vs baseline: 1.9882x; 1.0933x over previous
//
#include <hip/hip_runtime.h>

// Problem constants
#define BB 2048
#define TT 26
#define DIN 512
#define HH 512
#define EE 256
#define CC 97
#define SS 32
#define G4 2048   // 4*H
#define XK2 1024  // gates GEMM K: ctx(512) + h(512); ce folded into P lookup

typedef unsigned short u16;
typedef __bf16 bf16x8 __attribute__((ext_vector_type(8)));
typedef float f32x4 __attribute__((ext_vector_type(4)));

__device__ __forceinline__ float bf2f(u16 u) {
    return __uint_as_float(((unsigned int)u) << 16);
}
__device__ __forceinline__ u16 f2bf(float f) {  // RNE
    unsigned int u = __float_as_uint(f);
    u = u + 0x7FFFu + ((u >> 16) & 1u);
    return (u16)(u >> 16);
}
__device__ __forceinline__ float th_f(float x) {
    return 1.0f - 2.0f * __builtin_amdgcn_rcpf(__expf(2.0f * x) + 1.0f);
}
__device__ __forceinline__ float sig_f(float x) {
    return __builtin_amdgcn_rcpf(1.0f + __expf(-x));
}

// async global->LDS, 16B/lane; LDS base wave-uniform
__device__ __forceinline__ void async16(const u16* g, u16* l) {
    __builtin_amdgcn_global_load_lds(
        (const __attribute__((address_space(1))) unsigned int*)(g),
        (__attribute__((address_space(3))) unsigned int*)(l), 16, 0, 0);
}

// ---------------------------------------------------------------------------
// gemm128 (Hp): C[M,N] = A[M,K] @ W[N,K]^T, 128x128 tile, m97 staging, bf16 out
// ---------------------------------------------------------------------------
__global__ __launch_bounds__(256) void gemm128(
    const u16* __restrict__ A, int lda,
    const u16* __restrict__ W,
    u16* __restrict__ Cout, int ldc, int K)
{
    __shared__ __align__(16) u16 As[128 * 32];
    __shared__ __align__(16) u16 Ws[128 * 32];

    const int tid  = threadIdx.x;
    const int lane = tid & 63;
    const int wave = tid >> 6;
    const int m0 = blockIdx.y * 128;
    const int n0 = blockIdx.x * 128;

    const int srow = tid >> 2;
    const int scol = (tid & 3) * 8;
    const u16* Arow0 = A + (size_t)(m0 + srow) * lda + scol;
    const u16* Arow1 = A + (size_t)(m0 + 64 + srow) * lda + scol;
    const u16* Wrow0 = W + (size_t)(n0 + srow) * K + scol;
    const u16* Wrow1 = W + (size_t)(n0 + 64 + srow) * K + scol;
    u16* dstA0 = As + wave * 512;
    u16* dstA1 = As + 2048 + wave * 512;
    u16* dstW0 = Ws + wave * 512;
    u16* dstW1 = Ws + 2048 + wave * 512;

    const int wm = (wave >> 1) * 64;
    const int wn = (wave & 1) * 64;
    const int fr = lane & 15;
    const int fq = lane >> 4;

    f32x4 acc[4][4];
    #pragma unroll
    for (int i = 0; i < 4; i++)
        #pragma unroll
        for (int j = 0; j < 4; j++)
            #pragma unroll
            for (int r = 0; r < 4; r++) acc[i][j][r] = 0.0f;

    for (int k0 = 0; k0 < K; k0 += 32) {
        async16(Arow0 + k0, dstA0);
        async16(Arow1 + k0, dstA1);
        async16(Wrow0 + k0, dstW0);
        async16(Wrow1 + k0, dstW1);
        __syncthreads();
        bf16x8 af[4], bw[4];
        #pragma unroll
        for (int i = 0; i < 4; i++)
            af[i] = *(const bf16x8*)&As[(wm + i * 16 + fr) * 32 + fq * 8];
        #pragma unroll
        for (int j = 0; j < 4; j++)
            bw[j] = *(const bf16x8*)&Ws[(wn + j * 16 + fr) * 32 + fq * 8];
        #pragma unroll
        for (int i = 0; i < 4; i++)
            #pragma unroll
            for (int j = 0; j < 4; j++)
                acc[i][j] = __builtin_amdgcn_mfma_f32_16x16x32_bf16(
                    af[i], bw[j], acc[i][j], 0, 0, 0);
        __syncthreads();
    }

    #pragma unroll
    for (int j = 0; j < 4; j++) {
        int col = n0 + wn + j * 16 + fr;
        #pragma unroll
        for (int i = 0; i < 4; i++) {
            int row = m0 + wm + i * 16 + fq * 4;
            #pragma unroll
            for (int r = 0; r < 4; r++)
                Cout[(size_t)(row + r) * ldc + col] = f2bf(acc[i][j][r]);
        }
    }
}

// ---------------------------------------------------------------------------
// gen128: probs = hid[1..32] @ Wgen^T + b_gen.  M=65536 (s-major rows),
// N=128 (97 valid), K=512.  grid (1, 512).  out[b][s][c] scatter on store.
// ---------------------------------------------------------------------------
__global__ __launch_bounds__(256) void gen128(
    const u16* __restrict__ A,        // hid + B*H, rows stride 512
    const u16* __restrict__ Wg,       // [128][512] padded
    const float* __restrict__ bgen,   // [97] fp32
    float* __restrict__ out)
{
    __shared__ __align__(16) u16 As[128 * 32];
    __shared__ __align__(16) u16 Ws[128 * 32];

    const int tid  = threadIdx.x;
    const int lane = tid & 63;
    const int wave = tid >> 6;
    const int m0 = blockIdx.y * 128;

    const int srow = tid >> 2;
    const int scol = (tid & 3) * 8;
    const u16* Arow0 = A + (size_t)(m0 + srow) * HH + scol;
    const u16* Arow1 = A + (size_t)(m0 + 64 + srow) * HH + scol;
    const u16* Wrow0 = Wg + (size_t)srow * HH + scol;
    const u16* Wrow1 = Wg + (size_t)(64 + srow) * HH + scol;
    u16* dstA0 = As + wave * 512;
    u16* dstA1 = As + 2048 + wave * 512;
    u16* dstW0 = Ws + wave * 512;
    u16* dstW1 = Ws + 2048 + wave * 512;

    const int wm = (wave >> 1) * 64;
    const int wn = (wave & 1) * 64;
    const int fr = lane & 15;
    const int fq = lane >> 4;

    f32x4 acc[4][4];
    #pragma unroll
    for (int i = 0; i < 4; i++)
        #pragma unroll
        for (int j = 0; j < 4; j++)
            #pragma unroll
            for (int r = 0; r < 4; r++) acc[i][j][r] = 0.0f;

    for (int k0 = 0; k0 < HH; k0 += 32) {
        async16(Arow0 + k0, dstA0);
        async16(Arow1 + k0, dstA1);
        async16(Wrow0 + k0, dstW0);
        async16(Wrow1 + k0, dstW1);
        __syncthreads();
        bf16x8 af[4], bw[4];
        #pragma unroll
        for (int i = 0; i < 4; i++)
            af[i] = *(const bf16x8*)&As[(wm + i * 16 + fr) * 32 + fq * 8];
        #pragma unroll
        for (int j = 0; j < 4; j++)
            bw[j] = *(const bf16x8*)&Ws[(wn + j * 16 + fr) * 32 + fq * 8];
        #pragma unroll
        for (int i = 0; i < 4; i++)
            #pragma unroll
            for (int j = 0; j < 4; j++)
                acc[i][j] = __builtin_amdgcn_mfma_f32_16x16x32_bf16(
                    af[i], bw[j], acc[i][j], 0, 0, 0);
        __syncthreads();
    }

    #pragma unroll
    for (int j = 0; j < 4; j++) {
        int col = wn + j * 16 + fr;
        if (col < CC) {
            float bv = bgen[col];
            #pragma unroll
            for (int i = 0; i < 4; i++) {
                int row = m0 + wm + i * 16 + fq * 4;
                #pragma unroll
                for (int r = 0; r < 4; r++) {
                    int m = row + r;
                    int s = m >> 11, b = m & (BB - 1);
                    out[(size_t)b * (SS * CC) + s * CC + col] = acc[i][j][r] + bv;
                }
            }
        }
    }
}

// ---------------------------------------------------------------------------
// gates_lstm: gates = [ctx|h_s] @ Wcat^T (interleaved col=4h+g), epilogue adds
// bcat + P[char] and applies LSTM.  Tile 64(M)x128(N), grid (16,32)=512.
// h_{s+1} -> hnext (s-major hid buffer).
// ---------------------------------------------------------------------------
__global__ __launch_bounds__(256) void gates_lstm(
    const u16* __restrict__ ctx,    // [B][512]
    const u16* __restrict__ hprev,  // [B][512] (hid slot s)
    const u16* __restrict__ Wc,     // [2048][1024] interleaved
    const float* __restrict__ bcat, // [2048] interleaved
    const float* __restrict__ P,    // [128][2048] char-gate bias, interleaved
    const int* __restrict__ text,   // [B][SS]
    float* __restrict__ c,          // [B][512]
    u16* __restrict__ hnext,        // [B][512] (hid slot s+1)
    int s)
{
    __shared__ __align__(16) u16 As[64 * 32];    // 4 KB
    __shared__ __align__(16) u16 Ws[128 * 32];   // 8 KB
    __shared__ float gsm[64 * 68];               // 17 KB
    __shared__ int text_sm[64];

    const int tid  = threadIdx.x;
    const int lane = tid & 63;
    const int wave = tid >> 6;

    // XCD swizzle: per-XCD 8x8 region (A 8 strips + W 8 strips < 4 MB L2)
    int b   = blockIdx.y * gridDim.x + blockIdx.x;
    int xcd = b & 7, loc = b >> 3;
    int by = (xcd & 3) * 8 + (loc & 7);     // 0..31  (M tiles)
    int bx = (xcd >> 2) * 8 + (loc >> 3);   // 0..15  (N tiles)
    const int m0 = by * 64;
    const int n0 = bx * 128;

    if (tid < 64) text_sm[tid] = text[(m0 + tid) * SS + s];

    const int srow = tid >> 2;
    const int scol = (tid & 3) * 8;
    const u16* Actx  = ctx   + (size_t)(m0 + srow) * 512 + scol;
    const u16* Ahid  = hprev + (size_t)(m0 + srow) * 512 + scol;
    const u16* Wrow0 = Wc + (size_t)(n0 + srow) * XK2 + scol;
    const u16* Wrow1 = Wc + (size_t)(n0 + 64 + srow) * XK2 + scol;
    u16* dstA  = As + wave * 512;
    u16* dstW0 = Ws + wave * 512;
    u16* dstW1 = Ws + 2048 + wave * 512;

    const int wm = (wave & 1) * 32;   // 2x2 wave grid: 32M x 64N each
    const int wn = (wave >> 1) * 64;
    const int fr = lane & 15;
    const int fq = lane >> 4;

    f32x4 acc[2][4];
    #pragma unroll
    for (int i = 0; i < 2; i++)
        #pragma unroll
        for (int j = 0; j < 4; j++)
            #pragma unroll
            for (int r = 0; r < 4; r++) acc[i][j][r] = 0.0f;

    #pragma unroll
    for (int k0 = 0; k0 < XK2; k0 += 32) {
        const u16* asrc = (k0 < 512) ? (Actx + k0) : (Ahid + (k0 - 512));
        async16(asrc, dstA);
        async16(Wrow0 + k0, dstW0);
        async16(Wrow1 + k0, dstW1);
        __syncthreads();
        bf16x8 af[2], bw[4];
        #pragma unroll
        for (int i = 0; i < 2; i++)
            af[i] = *(const bf16x8*)&As[(wm + i * 16 + fr) * 32 + fq * 8];
        #pragma unroll
        for (int j = 0; j < 4; j++)
            bw[j] = *(const bf16x8*)&Ws[(wn + j * 16 + fr) * 32 + fq * 8];
        #pragma unroll
        for (int i = 0; i < 2; i++)
            #pragma unroll
            for (int j = 0; j < 4; j++)
                acc[i][j] = __builtin_amdgcn_mfma_f32_16x16x32_bf16(
                    af[i], bw[j], acc[i][j], 0, 0, 0);
        __syncthreads();
    }

    // Epilogue: two 64-col passes -> LDS, then fused LSTM (bias+P added here)
    #pragma unroll
    for (int p = 0; p < 2; p++) {
        if ((wave >> 1) == p) {
            #pragma unroll
            for (int j = 0; j < 4; j++) {
                int cl = j * 16 + fr;
                #pragma unroll
                for (int i = 0; i < 2; i++) {
                    int rl = wm + i * 16 + fq * 4;
                    #pragma unroll
                    for (int r = 0; r < 4; r++)
                        gsm[(rl + r) * 68 + cl] = acc[i][j][r];
                }
            }
        }
        __syncthreads();
        #pragma unroll
        for (int rr = 0; rr < 4; rr++) {
            int idx = rr * 256 + tid;
            int u = idx & 15, row = idx >> 4;
            int base = row * 68 + 4 * u;
            int hg = (n0 >> 2) + p * 16 + u;   // global h unit
            int c0 = 4 * hg;                    // interleaved gate col base
            int ch = text_sm[row];
            float4 bc = *(const float4*)(bcat + c0);
            float4 pv = *(const float4*)(P + (size_t)ch * G4 + c0);
            float ig = sig_f(gsm[base]     + bc.x + pv.x);
            float fg = sig_f(gsm[base + 1] + bc.y + pv.y);
            float gg = th_f (gsm[base + 2] + bc.z + pv.z);
            float og = sig_f(gsm[base + 3] + bc.w + pv.w);
            size_t ci = (size_t)(m0 + row) * HH + hg;
            float cn = fg * c[ci] + ig * gg;
            c[ci] = cn;
            hnext[(size_t)(m0 + row) * HH + hg] = f2bf(og * th_f(cn));
        }
        __syncthreads();
    }
}

// ---------------------------------------------------------------------------
// gemm64: 64x64-tile GEMM, fp32 out + bias. Used for ph (N=512,K=512) and the
// one-time P build (N=2048,K=256).
// ---------------------------------------------------------------------------
__global__ __launch_bounds__(256) void gemm64(
    const u16* __restrict__ A, int lda,
    const u16* __restrict__ W, int ldw,
    const float* __restrict__ bias,   // nullptr-free: pass zeros buffer or real
    float* __restrict__ Cout, int ldc, int K, int use_bias)
{
    __shared__ __align__(16) u16 As[64][32];
    __shared__ __align__(16) u16 Ws[64][32];

    const int tid  = threadIdx.x;
    const int lane = tid & 63;
    const int wave = tid >> 6;
    const int m0 = blockIdx.y * 64;
    const int n0 = blockIdx.x * 64;
    const int ar = tid >> 2;
    const int ac = (tid & 3) * 8;
    const int wm = (wave >> 1) * 32;
    const int wn = (wave & 1) * 32;
    const int fr = lane & 15;
    const int fq = lane >> 4;

    f32x4 acc[2][2];
    #pragma unroll
    for (int i = 0; i < 2; i++)
        #pragma unroll
        for (int j = 0; j < 2; j++)
            #pragma unroll
            for (int r = 0; r < 4; r++) acc[i][j][r] = 0.0f;

    const u16* Arow = A + (size_t)(m0 + ar) * lda;
    const u16* Wrow = W + (size_t)(n0 + ar) * ldw;

    for (int k0 = 0; k0 < K; k0 += 32) {
        *(uint4*)&As[ar][ac] = *(const uint4*)(Arow + k0 + ac);
        *(uint4*)&Ws[ar][ac] = *(const uint4*)(Wrow + k0 + ac);
        __syncthreads();
        bf16x8 af[2], bw[2];
        #pragma unroll
        for (int mm = 0; mm < 2; mm++)
            af[mm] = *(const bf16x8*)&As[wm + mm * 16 + fr][fq * 8];
        #pragma unroll
        for (int nn = 0; nn < 2; nn++)
            bw[nn] = *(const bf16x8*)&Ws[wn + nn * 16 + fr][fq * 8];
        #pragma unroll
        for (int mm = 0; mm < 2; mm++)
            #pragma unroll
            for (int nn = 0; nn < 2; nn++)
                acc[mm][nn] = __builtin_amdgcn_mfma_f32_16x16x32_bf16(
                    af[mm], bw[nn], acc[mm][nn], 0, 0, 0);
        __syncthreads();
    }

    #pragma unroll
    for (int nn = 0; nn < 2; nn++) {
        int col = n0 + wn + nn * 16 + fr;
        float bv = use_bias ? bias[col] : 0.0f;
        #pragma unroll
        for (int mm = 0; mm < 2; mm++) {
            int row = m0 + wm + mm * 16 + fq * 4;
            #pragma unroll
            for (int r = 0; r < 4; r++)
                Cout[(size_t)(row + r) * ldc + col] = acc[mm][nn][r] + bv;
        }
    }
}

// ---------------------------------------------------------------------------
// attn_step: e/softmax/context into ctx buffer.  1 block / batch row.
// ---------------------------------------------------------------------------
__global__ __launch_bounds__(256) void attn_step(
    const u16* __restrict__ Hp, const float* __restrict__ ph,
    const float* __restrict__ wscore, const u16* __restrict__ bH16,
    u16* __restrict__ ctx)
{
    const int b = blockIdx.x;
    const int tid = threadIdx.x, lane = tid & 63, wave = tid >> 6;
    __shared__ float e_sm[32];
    __shared__ float alpha_sm[32];

    const int h8 = lane * 8;
    float ph_r[8], ws_r[8];
    {
        float4 p0 = *(const float4*)(ph + (size_t)b * HH + h8);
        float4 p1 = *(const float4*)(ph + (size_t)b * HH + h8 + 4);
        ph_r[0]=p0.x; ph_r[1]=p0.y; ph_r[2]=p0.z; ph_r[3]=p0.w;
        ph_r[4]=p1.x; ph_r[5]=p1.y; ph_r[6]=p1.z; ph_r[7]=p1.w;
        float4 w0 = *(const float4*)(wscore + h8);
        float4 w1 = *(const float4*)(wscore + h8 + 4);
        ws_r[0]=w0.x; ws_r[1]=w0.y; ws_r[2]=w0.z; ws_r[3]=w0.w;
        ws_r[4]=w1.x; ws_r[5]=w1.y; ws_r[6]=w1.z; ws_r[7]=w1.w;
    }

    for (int t = wave; t < TT; t += 4) {
        uint4 hv = *(const uint4*)(Hp + ((size_t)b * TT + t) * HH + h8);
        const u16* hu = (const u16*)&hv;
        float sum = 0.0f;
        #pragma unroll
        for (int j = 0; j < 8; j++)
            sum += th_f(bf2f(hu[j]) + ph_r[j]) * ws_r[j];
        #pragma unroll
        for (int off = 32; off > 0; off >>= 1) sum += __shfl_down(sum, off);
        if (lane == 0) e_sm[t] = sum;
    }
    __syncthreads();

    if (tid == 0) {
        float mx = e_sm[0];
        for (int t = 1; t < TT; t++) mx = fmaxf(mx, e_sm[t]);
        float ssum = 0.0f;
        for (int t = 0; t < TT; t++) {
            float ev = __expf(e_sm[t] - mx);
            alpha_sm[t] = ev;
            ssum += ev;
        }
        float inv = 1.0f / ssum;
        for (int t = 0; t < TT; t++) alpha_sm[t] *= inv;
    }
    __syncthreads();

    {
        int d0 = tid * 2;
        float c0 = 0.0f, c1 = 0.0f;
        const u16* bb = bH16 + (size_t)b * TT * DIN + d0;
        #pragma unroll
        for (int t = 0; t < TT; t++) {
            unsigned int v = *(const unsigned int*)(bb + (size_t)t * DIN);
            float a = alpha_sm[t];
            c0 += a * bf2f((u16)(v & 0xffffu));
            c1 += a * bf2f((u16)(v >> 16));
        }
        unsigned int o = (unsigned int)f2bf(c0) | ((unsigned int)f2bf(c1) << 16);
        *(unsigned int*)(ctx + (size_t)b * 512 + d0) = o;
    }
}

// ---------------------------------------------------------------------------
// prep: bH16 cast (separate, big) + prep_all (everything else, one launch)
// ---------------------------------------------------------------------------
__global__ __launch_bounds__(256) void cast_f32_bf16(
    const float* __restrict__ src, u16* __restrict__ dst, int n)
{
    int i = (blockIdx.x * 256 + threadIdx.x) * 4;
    if (i < n) {
        float4 v = *(const float4*)(src + i);
        ushort4 o;
        o.x = f2bf(v.x); o.y = f2bf(v.y); o.z = f2bf(v.z); o.w = f2bf(v.w);
        *(ushort4*)(dst + i) = o;
    }
}

__global__ __launch_bounds__(256) void prep_all(
    const float* __restrict__ W_ih, const float* __restrict__ W_hh,
    const float* __restrict__ b_ih, const float* __restrict__ b_hh,
    const float* __restrict__ b_h2h, const float* __restrict__ emb,
    const float* __restrict__ W_i2h, const float* __restrict__ W_h2h,
    const float* __restrict__ W_gen,
    u16* __restrict__ Wcat, u16* __restrict__ Wce16, u16* __restrict__ emb16,
    u16* __restrict__ Wgen16, u16* __restrict__ Wi2h16, u16* __restrict__ Wh2h16,
    float* __restrict__ bcat, float* __restrict__ cst, u16* __restrict__ hid0,
    float* __restrict__ ph)
{
    int i = blockIdx.x * 256 + threadIdx.x;   // grid covers 2,097,152

    // Wcat [2048][1024] interleaved row np=4h+g: [W_ih[:, :512] | W_hh]
    {
        int np = i >> 10, k = i & (XK2 - 1);
        int h = np >> 2, g = np & 3;
        int n = g * HH + h;
        float v = (k < 512) ? W_ih[(size_t)n * (DIN + EE) + k]
                            : W_hh[(size_t)n * HH + (k - 512)];
        Wcat[(size_t)i] = f2bf(v);
    }
    // Wce16 [2048][256] interleaved: W_ih[:, 512:768]
    if (i < G4 * EE) {
        int np = i >> 8, e = i & (EE - 1);
        int h = np >> 2, g = np & 3;
        int n = g * HH + h;
        Wce16[i] = f2bf(W_ih[(size_t)n * (DIN + EE) + DIN + e]);
    }
    // emb16 [128][256], rows >= 97 zeroed
    if (i < 128 * EE) {
        int ch = i >> 8, e = i & (EE - 1);
        emb16[i] = (ch < CC) ? f2bf(emb[(size_t)ch * EE + e]) : (u16)0;
    }
    // Wgen16 [128][512], rows >= 97 zeroed
    if (i < 128 * HH) {
        int n = i >> 9, k = i & (HH - 1);
        Wgen16[i] = (n < CC) ? f2bf(W_gen[(size_t)n * HH + k]) : (u16)0;
    }
    // Wi2h16, Wh2h16 plain casts
    if (i < HH * DIN) Wi2h16[i] = f2bf(W_i2h[i]);
    if (i < HH * HH)  Wh2h16[i] = f2bf(W_h2h[i]);
    // bcat interleaved
    if (i < G4) {
        int h = i >> 2, g = i & 3;
        int n = g * HH + h;
        bcat[i] = b_ih[n] + b_hh[n];
    }
    // state init: c=0, hid slot0 = 0, ph = b_h2h (h0 = 0)
    if (i < BB * HH) {
        cst[i] = 0.0f;
        hid0[i] = 0;
        ph[i] = b_h2h[i & (HH - 1)];
    }
}

// ---------------------------------------------------------------------------
// Workspace layout (bytes)  — total ~196 MB (ws ~436 MB per fill counter)
// ---------------------------------------------------------------------------
#define BH16_OFF  ((size_t)0)             // bf16 [B*T, DIN]   54,525,952
#define HP_OFF    ((size_t)54525952)      // bf16 [B*T, H]     54,525,952
#define HID_OFF   ((size_t)109051904)     // bf16 [33][B][H]   69,206,016
#define CTX_OFF   ((size_t)178257920)     // bf16 [B][512]      2,097,152
#define WCAT_OFF  ((size_t)180355072)     // bf16 [2048][1024]  4,194,304
#define WCE_OFF   ((size_t)184549376)     // bf16 [2048][256]   1,048,576
#define EMB16_OFF ((size_t)185597952)     // bf16 [128][256]       65,536
#define WGEN_OFF  ((size_t)185663488)     // bf16 [128][512]      131,072
#define WI2H_OFF  ((size_t)185794560)     // bf16 [512][512]      524,288
#define WH2H_OFF  ((size_t)186318848)     // bf16 [512][512]      524,288
#define BCAT_OFF  ((size_t)186843136)     // f32 [2048]             8,192
#define P_OFF     ((size_t)186851328)     // f32 [128][2048]    1,048,576
#define PH_OFF    ((size_t)187899904)     // f32 [B][512]       4,194,304
#define CST_OFF   ((size_t)192094208)     // f32 [B][512]       4,194,304

extern "C" void kernel_launch(void* const* d_in, const int* in_sizes, int n_in,
                              void* d_out, int out_size, void* d_ws, size_t ws_size,
                              hipStream_t stream)
{
    const float* batch_H = (const float*)d_in[0];
    const int*   text    = (const int*)d_in[1];
    const float* W_i2h   = (const float*)d_in[2];
    const float* W_h2h   = (const float*)d_in[3];
    const float* b_h2h   = (const float*)d_in[4];
    const float* w_score = (const float*)d_in[5];
    const float* W_ih    = (const float*)d_in[6];
    const float* W_hh    = (const float*)d_in[7];
    const float* b_ih    = (const float*)d_in[8];
    const float* b_hh    = (const float*)d_in[9];
    const float* W_gen   = (const float*)d_in[10];
    const float* b_gen   = (const float*)d_in[11];
    const float* emb     = (const float*)d_in[12];

    char* ws = (char*)d_ws;
    u16*   bH16   = (u16*)(ws + BH16_OFF);
    u16*   Hp     = (u16*)(ws + HP_OFF);
    u16*   hid    = (u16*)(ws + HID_OFF);
    u16*   ctx    = (u16*)(ws + CTX_OFF);
    u16*   Wcat   = (u16*)(ws + WCAT_OFF);
    u16*   Wce16  = (u16*)(ws + WCE_OFF);
    u16*   emb16  = (u16*)(ws + EMB16_OFF);
    u16*   Wgen16 = (u16*)(ws + WGEN_OFF);
    u16*   Wi2h16 = (u16*)(ws + WI2H_OFF);
    u16*   Wh2h16 = (u16*)(ws + WH2H_OFF);
    float* bcat   = (float*)(ws + BCAT_OFF);
    float* P      = (float*)(ws + P_OFF);
    float* ph     = (float*)(ws + PH_OFF);
    float* cst    = (float*)(ws + CST_OFF);
    float* out    = (float*)d_out;

    // prep (3 launches)
    cast_f32_bf16<<<dim3((BB * TT * DIN / 4 + 255) / 256), 256, 0, stream>>>(
        batch_H, bH16, BB * TT * DIN);
    prep_all<<<dim3((G4 * XK2) / 256), 256, 0, stream>>>(
        W_ih, W_hh, b_ih, b_hh, b_h2h, emb, W_i2h, W_h2h, W_gen,
        Wcat, Wce16, emb16, Wgen16, Wi2h16, Wh2h16, bcat, cst, hid, ph);
    // P[128][2048] = emb16 @ Wce16^T  (fp32 out)
    gemm64<<<dim3(G4 / 64, 128 / 64), 256, 0, stream>>>(
        emb16, EE, Wce16, EE, nullptr, P, G4, EE, 0);

    // Hp = batch_H @ W_i2h^T
    gemm128<<<dim3(HH / 128, (BB * TT) / 128), 256, 0, stream>>>(
        bH16, DIN, Wi2h16, Hp, HH, DIN);

    for (int s = 0; s < SS; s++) {
        u16* hprev = hid + (size_t)s * BB * HH;
        u16* hnext = hid + (size_t)(s + 1) * BB * HH;

        attn_step<<<dim3(BB), 256, 0, stream>>>(Hp, ph, w_score, bH16, ctx);

        gates_lstm<<<dim3(G4 / 128, BB / 64), 256, 0, stream>>>(
            ctx, hprev, Wcat, bcat, P, text, cst, hnext, s);

        // ph = h_{s+1} @ W_h2h^T + b_h2h
        gemm64<<<dim3(HH / 64, BB / 64), 256, 0, stream>>>(
            hnext, HH, Wh2h16, HH, b_h2h, ph, HH, HH, 1);
    }

    // probs = hid[1..32] @ W_gen^T + b_gen  (one big GEMM, scatter store)
    gen128<<<dim3(1, (SS * BB) / 128), 256, 0, stream>>>(
        hid + (size_t)BB * HH, Wgen16, b_gen, out);
}